// Round 10
// baseline (16448.932 us; speedup 1.0000x reference)
//
#include <hip/hip_runtime.h>

#define N_NODES 50000
#define N_EDGES 1600000
#define N_GRAPHS 1024
#define HID 64
#define EDGE_F 16
#define LN_EPS 1e-5f

__device__ __forceinline__ float silu_f(float x) {
    return x / (1.0f + __expf(-x));
}

// acc[k] += scale * x[j] * w[j*HID + k]; w accesses wave-uniform -> s_load + SGPR-operand v_fma.
template<int NJ4>
__device__ __forceinline__ void gemv_acc(const float4* __restrict__ x,
                                         const float* __restrict__ w,
                                         float scale, float* __restrict__ acc) {
    for (int j4 = 0; j4 < NJ4; ++j4) {
        float4 v = x[j4];
        v.x *= scale; v.y *= scale; v.z *= scale; v.w *= scale;
        const float* wr = w + j4 * 4 * HID;
        #pragma unroll
        for (int k = 0; k < HID; ++k) acc[k] = fmaf(v.x, wr[k],         acc[k]);
        #pragma unroll
        for (int k = 0; k < HID; ++k) acc[k] = fmaf(v.y, wr[HID + k],   acc[k]);
        #pragma unroll
        for (int k = 0; k < HID; ++k) acc[k] = fmaf(v.z, wr[2*HID + k], acc[k]);
        #pragma unroll
        for (int k = 0; k < HID; ++k) acc[k] = fmaf(v.w, wr[3*HID + k], acc[k]);
    }
}

__device__ __forceinline__ void edge_msg_body(int e,
    const float* __restrict__ h, const float* __restrict__ pos,
    const float* __restrict__ edge_attr, const int* __restrict__ src,
    const int* __restrict__ dst, const float* __restrict__ Wm,
    const float* __restrict__ bm, float* __restrict__ acc, int* d_out)
{
    int s = src[e], d = dst[e];
    *d_out = d;
    float px = pos[3*s+0] - pos[3*d+0];
    float py = pos[3*s+1] - pos[3*d+1];
    float pz = pos[3*s+2] - pos[3*d+2];
    float dij = sqrtf(fmaxf(px*px + py*py + pz*pz, 1e-8f));

    #pragma unroll
    for (int k = 0; k < HID; ++k) acc[k] = bm[k];
    gemv_acc<16>((const float4*)(h + (size_t)s * HID), Wm,          1.0f, acc);
    gemv_acc<16>((const float4*)(h + (size_t)d * HID), Wm + 64*HID, 1.0f, acc);
    {
        const float* wr = Wm + 128*HID;
        #pragma unroll
        for (int k = 0; k < HID; ++k) acc[k] = fmaf(dij, wr[k], acc[k]);
    }
    gemv_acc<4>((const float4*)(edge_attr + (size_t)e * EDGE_F), Wm + 129*HID, 1.0f, acc);
}

// ---------- fast path: CSR aggregation, no f32 atomics ----------

// messages -> dense msg[E][64], plain stores
__global__ __launch_bounds__(256) void edge_msg_kernel(
    const float* __restrict__ h, const float* __restrict__ pos,
    const float* __restrict__ edge_attr, const int* __restrict__ src,
    const int* __restrict__ dst, const float* __restrict__ Wm,
    const float* __restrict__ bm, float* __restrict__ msg)
{
    int e = blockIdx.x * 256 + threadIdx.x;
    if (e >= N_EDGES) return;
    float acc[HID]; int d;
    edge_msg_body(e, h, pos, edge_attr, src, dst, Wm, bm, acc, &d);
    float4* mo = (float4*)(msg + (size_t)e * HID);
    #pragma unroll
    for (int k4 = 0; k4 < 16; ++k4)
        mo[k4] = make_float4(silu_f(acc[4*k4+0]), silu_f(acc[4*k4+1]),
                             silu_f(acc[4*k4+2]), silu_f(acc[4*k4+3]));
}

__global__ __launch_bounds__(256) void csr_count(const int* __restrict__ dst, int* __restrict__ deg) {
    int e = blockIdx.x * 256 + threadIdx.x;
    if (e < N_EDGES) atomicAdd(&deg[dst[e]], 1);
}

__global__ __launch_bounds__(256) void scan_blocks(const int* __restrict__ deg,
                                                   int* __restrict__ row_ptr,
                                                   int* __restrict__ partial) {
    __shared__ int sm[256];
    int i = blockIdx.x * 256 + threadIdx.x;
    int v = (i < N_NODES) ? deg[i] : 0;
    sm[threadIdx.x] = v;
    __syncthreads();
    for (int off = 1; off < 256; off <<= 1) {
        int t = (threadIdx.x >= off) ? sm[threadIdx.x - off] : 0;
        __syncthreads();
        sm[threadIdx.x] += t;
        __syncthreads();
    }
    if (i <= N_NODES) row_ptr[i] = sm[threadIdx.x] - v;  // exclusive
    if (threadIdx.x == 255) partial[blockIdx.x] = sm[255];
}

__global__ __launch_bounds__(256) void scan_partials(const int* __restrict__ partial,
                                                     int* __restrict__ pscan, int nb) {
    __shared__ int sm[256];
    int v = (threadIdx.x < nb) ? partial[threadIdx.x] : 0;
    sm[threadIdx.x] = v;
    __syncthreads();
    for (int off = 1; off < 256; off <<= 1) {
        int t = (threadIdx.x >= off) ? sm[threadIdx.x - off] : 0;
        __syncthreads();
        sm[threadIdx.x] += t;
        __syncthreads();
    }
    pscan[threadIdx.x] = sm[threadIdx.x] - v;  // exclusive
}

__global__ __launch_bounds__(256) void add_offsets(int* __restrict__ row_ptr,
                                                   const int* __restrict__ pscan) {
    int i = blockIdx.x * 256 + threadIdx.x;
    if (i <= N_NODES) row_ptr[i] += pscan[blockIdx.x];
}

__global__ __launch_bounds__(256) void csr_fill(const int* __restrict__ dst,
                                                const int* __restrict__ row_ptr,
                                                int* __restrict__ fill, int* __restrict__ eids) {
    int e = blockIdx.x * 256 + threadIdx.x;
    if (e >= N_EDGES) return;
    int d = dst[e];
    int slot = atomicAdd(&fill[d], 1);
    eids[row_ptr[d] + slot] = e;
}

// one 64-lane wave per node, lane = feature: CSR-gather msgs + Wu GEMV (shfl) + silu + LN
__global__ __launch_bounds__(256) void agg_node_kernel(
    const float* __restrict__ msg, const int* __restrict__ row_ptr,
    const int* __restrict__ eids, const float* __restrict__ Wu,
    const float* __restrict__ bu, const float* __restrict__ g,
    const float* __restrict__ b, float* __restrict__ hout)
{
    int wid = (blockIdx.x * 256 + threadIdx.x) >> 6;
    int lane = threadIdx.x & 63;
    if (wid >= N_NODES) return;
    int beg = row_ptr[wid], end = row_ptr[wid + 1];

    float acc = 0.f;
    for (int c = beg; c < end; c += 64) {
        int m = min(64, end - c);
        int my = (c + lane < end) ? eids[c + lane] : 0;
        for (int t = 0; t < m; ++t) {
            int eid = __shfl(my, t);
            acc += msg[(size_t)eid * HID + lane];
        }
    }
    acc *= 0.1f;

    float u = bu[lane];
    #pragma unroll
    for (int j = 0; j < HID; ++j) {
        float aj = __shfl(acc, j);
        u = fmaf(aj, Wu[j * HID + lane], u);
    }
    u = silu_f(u);

    float s = u;
    #pragma unroll
    for (int m2 = 32; m2 > 0; m2 >>= 1) s += __shfl_xor(s, m2);
    float mu = s * (1.0f / HID);
    float d = u - mu;
    float vs = d * d;
    #pragma unroll
    for (int m2 = 32; m2 > 0; m2 >>= 1) vs += __shfl_xor(vs, m2);
    float rs = rsqrtf(vs * (1.0f / HID) + LN_EPS);
    hout[(size_t)wid * HID + lane] = fmaf(g[lane], d * rs, b[lane]);
}

// segmented graph-sum: wave handles 64 consecutive (gid-sorted) nodes, ~2 atomics/run
__global__ __launch_bounds__(256) void gsum_seg(const float* __restrict__ h,
                                                const int* __restrict__ gid,
                                                float* __restrict__ gf) {
    int wv = (blockIdx.x * 256 + threadIdx.x) >> 6;
    int lane = threadIdx.x & 63;
    int base = wv * 64;
    if (base >= N_NODES) return;
    int endn = min(base + 64, N_NODES);
    int cur = gid[base];
    float acc = 0.f;
    for (int n = base; n < endn; ++n) {
        int gg = gid[n];  // wave-uniform
        float v = h[(size_t)n * HID + lane] * 0.1f;
        if (gg != cur) {
            atomicAdd(&gf[(size_t)cur * HID + lane], acc);
            acc = v; cur = gg;
        } else acc += v;
    }
    atomicAdd(&gf[(size_t)cur * HID + lane], acc);
}

// ---------- fallback path (atomic aggregation) ----------

__global__ __launch_bounds__(256) void edge_kernel(
    const float* __restrict__ h, const float* __restrict__ pos,
    const float* __restrict__ edge_attr, const int* __restrict__ src,
    const int* __restrict__ dst, const float* __restrict__ Wm,
    const float* __restrict__ bm, float* __restrict__ agg)
{
    int e = blockIdx.x * 256 + threadIdx.x;
    if (e >= N_EDGES) return;
    float acc[HID]; int d;
    edge_msg_body(e, h, pos, edge_attr, src, dst, Wm, bm, acc, &d);
    float* a = agg + (size_t)d * HID;
    #pragma unroll
    for (int k = 0; k < HID; ++k) atomicAdd(a + k, silu_f(acc[k]));
}

__global__ __launch_bounds__(256) void node_kernel(
    float* __restrict__ agg, const float* __restrict__ Wu,
    const float* __restrict__ bu, const float* __restrict__ g,
    const float* __restrict__ b)
{
    int n = blockIdx.x * 256 + threadIdx.x;
    if (n >= N_NODES) return;
    float acc[HID];
    #pragma unroll
    for (int k = 0; k < HID; ++k) acc[k] = bu[k];
    gemv_acc<16>((const float4*)(agg + (size_t)n * HID), Wu, 0.1f, acc);
    float mu = 0.f;
    #pragma unroll
    for (int k = 0; k < HID; ++k) { acc[k] = silu_f(acc[k]); mu += acc[k]; }
    mu *= (1.0f / HID);
    float var = 0.f;
    #pragma unroll
    for (int k = 0; k < HID; ++k) { float t = acc[k] - mu; var += t * t; }
    var *= (1.0f / HID);
    float rs = rsqrtf(var + LN_EPS);
    float* o = agg + (size_t)n * HID;
    #pragma unroll
    for (int k = 0; k < HID; ++k) o[k] = fmaf(g[k], (acc[k] - mu) * rs, b[k]);
}

__global__ __launch_bounds__(256) void gsum_kernel(
    const float* __restrict__ h, const int* __restrict__ gid, float* __restrict__ gf)
{
    int t = blockIdx.x * 256 + threadIdx.x;
    int n = t >> 6, k = t & 63;
    if (n >= N_NODES) return;
    atomicAdd(gf + gid[n] * HID + k, h[(size_t)n * HID + k] * 0.1f);
}

__global__ __launch_bounds__(256) void head_kernel(
    const float* __restrict__ gf, const float* __restrict__ Wh1,
    const float* __restrict__ bh1, const float* __restrict__ Wh2,
    const float* __restrict__ bh2, float* __restrict__ out)
{
    int gi = blockIdx.x * 256 + threadIdx.x;
    if (gi >= N_GRAPHS) return;
    float x[HID];
    const float4* xr = (const float4*)(gf + (size_t)gi * HID);
    #pragma unroll
    for (int j4 = 0; j4 < 16; ++j4) {
        float4 v = xr[j4];
        x[4*j4] = v.x; x[4*j4+1] = v.y; x[4*j4+2] = v.z; x[4*j4+3] = v.w;
    }
    float o = bh2[0];
    #pragma unroll 4
    for (int j = 0; j < 32; ++j) {
        float hs_ = bh1[j];
        #pragma unroll
        for (int k = 0; k < HID; ++k) hs_ = fmaf(x[k], Wh1[k*32 + j], hs_);
        o = fmaf(silu_f(hs_), Wh2[j], o);
    }
    out[gi] = o;
}

extern "C" void kernel_launch(void* const* d_in, const int* in_sizes, int n_in,
                              void* d_out, int out_size, void* d_ws, size_t ws_size,
                              hipStream_t stream)
{
    const float* node_attr = (const float*)d_in[0];
    const float* pos       = (const float*)d_in[1];
    const float* edge_attr = (const float*)d_in[2];
    const int*   src       = (const int*)d_in[3];
    const int*   dst       = (const int*)d_in[4];
    const int*   gid       = (const int*)d_in[5];
    const float* Wm        = (const float*)d_in[6];
    const float* bm        = (const float*)d_in[7];
    const float* Wu        = (const float*)d_in[8];
    const float* bu        = (const float*)d_in[9];
    const float* ln_g      = (const float*)d_in[10];
    const float* ln_b      = (const float*)d_in[11];
    const float* Wh1       = (const float*)d_in[12];
    const float* bh1       = (const float*)d_in[13];
    const float* Wh2       = (const float*)d_in[14];
    const float* bh2       = (const float*)d_in[15];
    float* out = (float*)d_out;

    const int EB  = N_EDGES / 256;               // 6250
    const int NB  = (N_NODES + 255) / 256;       // 196
    const int SB  = (N_NODES + 1 + 255) / 256;   // 196 (covers row_ptr[N])

    // fast-path workspace layout
    float* msg = (float*)d_ws;                              // E*64 f32
    float* B1  = msg + (size_t)N_EDGES * HID;               // N*64
    float* B2  = B1 + (size_t)N_NODES * HID;                // N*64
    float* gf  = B2 + (size_t)N_NODES * HID;                // G*64
    int* deg   = (int*)(gf + (size_t)N_GRAPHS * HID);       // N
    int* fill  = deg + N_NODES;                              // N
    int* rp    = fill + N_NODES;                             // N+1
    int* part  = rp + N_NODES + 1;                           // 256
    int* pscan = part + 256;                                 // 256
    int* eids  = pscan + 256;                                // E
    size_t needed = ((size_t)(eids + N_EDGES) - (size_t)d_ws);

    if (ws_size >= needed) {
        hipMemsetAsync(deg, 0, (size_t)N_NODES * 2 * sizeof(int), stream);  // deg + fill
        csr_count<<<EB, 256, 0, stream>>>(dst, deg);
        scan_blocks<<<SB, 256, 0, stream>>>(deg, rp, part);
        scan_partials<<<1, 256, 0, stream>>>(part, pscan, SB);
        add_offsets<<<SB, 256, 0, stream>>>(rp, pscan);
        csr_fill<<<EB, 256, 0, stream>>>(dst, rp, fill, eids);

        const float* hin = node_attr;
        float* bufs[3] = { B1, B2, B1 };
        const int ANB = ((N_NODES * 64) + 255) / 256;  // 12500
        for (int i = 0; i < 3; ++i) {
            edge_msg_kernel<<<EB, 256, 0, stream>>>(hin, pos, edge_attr, src, dst,
                                                    Wm + (size_t)i * 145 * HID, bm + i * HID, msg);
            agg_node_kernel<<<ANB, 256, 0, stream>>>(msg, rp, eids,
                                                     Wu + (size_t)i * HID * HID, bu + i * HID,
                                                     ln_g + i * HID, ln_b + i * HID, bufs[i]);
            hin = bufs[i];
        }
        hipMemsetAsync(gf, 0, (size_t)N_GRAPHS * HID * sizeof(float), stream);
        const int GSB = ((((N_NODES + 63) / 64) * 64) + 255) / 256;
        gsum_seg<<<GSB, 256, 0, stream>>>(hin, gid, gf);
        head_kernel<<<(N_GRAPHS + 255) / 256, 256, 0, stream>>>(gf, Wh1, bh1, Wh2, bh2, out);
    } else {
        // fallback: atomic aggregation, needs only B1',B2',gf'
        float* fB1 = (float*)d_ws;
        float* fB2 = fB1 + (size_t)N_NODES * HID;
        float* fgf = fB2 + (size_t)N_NODES * HID;
        const float* hin = node_attr;
        float* bufs[3] = { fB1, fB2, fB1 };
        for (int i = 0; i < 3; ++i) {
            float* agg = bufs[i];
            hipMemsetAsync(agg, 0, (size_t)N_NODES * HID * sizeof(float), stream);
            edge_kernel<<<EB, 256, 0, stream>>>(hin, pos, edge_attr, src, dst,
                                                Wm + (size_t)i * 145 * HID, bm + i * HID, agg);
            node_kernel<<<NB, 256, 0, stream>>>(agg, Wu + (size_t)i * HID * HID, bu + i * HID,
                                                ln_g + i * HID, ln_b + i * HID);
            hin = agg;
        }
        hipMemsetAsync(fgf, 0, (size_t)N_GRAPHS * HID * sizeof(float), stream);
        gsum_kernel<<<(N_NODES * 64) / 256, 256, 0, stream>>>(hin, gid, fgf);
        head_kernel<<<(N_GRAPHS + 255) / 256, 256, 0, stream>>>(fgf, Wh1, bh1, Wh2, bh2, out);
    }
}

// Round 12
// 2632.596 us; speedup vs baseline: 6.2482x; 6.2482x over previous
//
#include <hip/hip_runtime.h>

#define N_NODES 50000
#define N_EDGES 1600000
#define N_GRAPHS 1024
#define HID 64
#define EDGE_F 16
#define LN_EPS 1e-5f

__device__ __forceinline__ float silu_f(float x) {
    return x / (1.0f + __expf(-x));
}

// acc[k] += scale * x[j] * w[j*HID + k]; w accesses wave-uniform -> s_load + SGPR-operand v_fma.
template<int NJ4>
__device__ __forceinline__ void gemv_acc(const float4* __restrict__ x,
                                         const float* __restrict__ w,
                                         float scale, float* __restrict__ acc) {
    for (int j4 = 0; j4 < NJ4; ++j4) {
        float4 v = x[j4];
        v.x *= scale; v.y *= scale; v.z *= scale; v.w *= scale;
        const float* wr = w + j4 * 4 * HID;
        #pragma unroll
        for (int k = 0; k < HID; ++k) acc[k] = fmaf(v.x, wr[k],         acc[k]);
        #pragma unroll
        for (int k = 0; k < HID; ++k) acc[k] = fmaf(v.y, wr[HID + k],   acc[k]);
        #pragma unroll
        for (int k = 0; k < HID; ++k) acc[k] = fmaf(v.z, wr[2*HID + k], acc[k]);
        #pragma unroll
        for (int k = 0; k < HID; ++k) acc[k] = fmaf(v.w, wr[3*HID + k], acc[k]);
    }
}

__device__ __forceinline__ void edge_msg_body(int e,
    const float* __restrict__ h, const float* __restrict__ pos,
    const float* __restrict__ edge_attr, const int* __restrict__ src,
    const int* __restrict__ dst, const float* __restrict__ Wm,
    const float* __restrict__ bm, float* __restrict__ acc, int* d_out)
{
    int s = src[e], d = dst[e];
    *d_out = d;
    float px = pos[3*s+0] - pos[3*d+0];
    float py = pos[3*s+1] - pos[3*d+1];
    float pz = pos[3*s+2] - pos[3*d+2];
    float dij = sqrtf(fmaxf(px*px + py*py + pz*pz, 1e-8f));

    #pragma unroll
    for (int k = 0; k < HID; ++k) acc[k] = bm[k];
    gemv_acc<16>((const float4*)(h + (size_t)s * HID), Wm,          1.0f, acc);
    gemv_acc<16>((const float4*)(h + (size_t)d * HID), Wm + 64*HID, 1.0f, acc);
    {
        const float* wr = Wm + 128*HID;
        #pragma unroll
        for (int k = 0; k < HID; ++k) acc[k] = fmaf(dij, wr[k], acc[k]);
    }
    gemv_acc<4>((const float4*)(edge_attr + (size_t)e * EDGE_F), Wm + 129*HID, 1.0f, acc);
}

// ---------- CSR build ----------

__global__ __launch_bounds__(256) void csr_count(const int* __restrict__ dst, int* __restrict__ deg) {
    int e = blockIdx.x * 256 + threadIdx.x;
    if (e < N_EDGES) atomicAdd(&deg[dst[e]], 1);
}

__global__ __launch_bounds__(256) void scan_blocks(const int* __restrict__ deg,
                                                   int* __restrict__ row_ptr,
                                                   int* __restrict__ partial) {
    __shared__ int sm[256];
    int i = blockIdx.x * 256 + threadIdx.x;
    int v = (i < N_NODES) ? deg[i] : 0;
    sm[threadIdx.x] = v;
    __syncthreads();
    for (int off = 1; off < 256; off <<= 1) {
        int t = (threadIdx.x >= off) ? sm[threadIdx.x - off] : 0;
        __syncthreads();
        sm[threadIdx.x] += t;
        __syncthreads();
    }
    if (i <= N_NODES) row_ptr[i] = sm[threadIdx.x] - v;  // exclusive
    if (threadIdx.x == 255) partial[blockIdx.x] = sm[255];
}

__global__ __launch_bounds__(256) void scan_partials(const int* __restrict__ partial,
                                                     int* __restrict__ pscan, int nb) {
    __shared__ int sm[256];
    int v = (threadIdx.x < nb) ? partial[threadIdx.x] : 0;
    sm[threadIdx.x] = v;
    __syncthreads();
    for (int off = 1; off < 256; off <<= 1) {
        int t = (threadIdx.x >= off) ? sm[threadIdx.x - off] : 0;
        __syncthreads();
        sm[threadIdx.x] += t;
        __syncthreads();
    }
    pscan[threadIdx.x] = sm[threadIdx.x] - v;  // exclusive
}

__global__ __launch_bounds__(256) void add_offsets(int* __restrict__ row_ptr,
                                                   const int* __restrict__ pscan) {
    int i = blockIdx.x * 256 + threadIdx.x;
    if (i <= N_NODES) row_ptr[i] += pscan[blockIdx.x];
}

__global__ __launch_bounds__(256) void csr_fill(const int* __restrict__ dst,
                                                const int* __restrict__ row_ptr,
                                                int* __restrict__ fill, int* __restrict__ eids) {
    int e = blockIdx.x * 256 + threadIdx.x;
    if (e >= N_EDGES) return;
    int d = dst[e];
    int slot = atomicAdd(&fill[d], 1);
    eids[row_ptr[d] + slot] = e;
}

// ---------- chunked fast path ----------

// thread t in [t0,t1): compute message for edge eids[t], write to msg[t-t0] (256B row store)
__global__ __launch_bounds__(256) void edge_msg_sorted(
    const float* __restrict__ h, const float* __restrict__ pos,
    const float* __restrict__ edge_attr, const int* __restrict__ src,
    const int* __restrict__ dst, const int* __restrict__ eids,
    const float* __restrict__ Wm, const float* __restrict__ bm,
    float* __restrict__ msg, int t0, int t1)
{
    int t = t0 + blockIdx.x * 256 + threadIdx.x;
    if (t >= t1) return;
    int e = eids[t];
    float acc[HID]; int d;
    edge_msg_body(e, h, pos, edge_attr, src, dst, Wm, bm, acc, &d);
    float4* mo = (float4*)(msg + (size_t)(t - t0) * HID);
    #pragma unroll
    for (int k4 = 0; k4 < 16; ++k4)
        mo[k4] = make_float4(silu_f(acc[4*k4+0]), silu_f(acc[4*k4+1]),
                             silu_f(acc[4*k4+2]), silu_f(acc[4*k4+3]));
}

// wave per node, lane = feature: sum contiguous msg rows in [rp[n],rp[n+1]) ∩ [t0,t1), += into aggbuf
__global__ __launch_bounds__(256) void agg_chunk(
    const float* __restrict__ msg, const int* __restrict__ row_ptr,
    float* __restrict__ aggbuf, int t0, int t1)
{
    int wid = (blockIdx.x * 256 + threadIdx.x) >> 6;
    int lane = threadIdx.x & 63;
    if (wid >= N_NODES) return;
    int beg = max(row_ptr[wid], t0);
    int end = min(row_ptr[wid + 1], t1);
    if (beg >= end) return;
    float acc = 0.f;
    for (int t = beg; t < end; ++t)
        acc += msg[(size_t)(t - t0) * HID + lane];
    aggbuf[(size_t)wid * HID + lane] += acc;
}

// one thread per node: u = silu((agg/10) @ Wu + bu); h_out = LN(u)*g + b. In-place on agg.
__global__ __launch_bounds__(256) void node_kernel(
    float* __restrict__ agg, const float* __restrict__ Wu,
    const float* __restrict__ bu, const float* __restrict__ g,
    const float* __restrict__ b)
{
    int n = blockIdx.x * 256 + threadIdx.x;
    if (n >= N_NODES) return;
    float acc[HID];
    #pragma unroll
    for (int k = 0; k < HID; ++k) acc[k] = bu[k];
    gemv_acc<16>((const float4*)(agg + (size_t)n * HID), Wu, 0.1f, acc);
    float mu = 0.f;
    #pragma unroll
    for (int k = 0; k < HID; ++k) { acc[k] = silu_f(acc[k]); mu += acc[k]; }
    mu *= (1.0f / HID);
    float var = 0.f;
    #pragma unroll
    for (int k = 0; k < HID; ++k) { float t = acc[k] - mu; var += t * t; }
    var *= (1.0f / HID);
    float rs = rsqrtf(var + LN_EPS);
    float* o = agg + (size_t)n * HID;
    #pragma unroll
    for (int k = 0; k < HID; ++k) o[k] = fmaf(g[k], (acc[k] - mu) * rs, b[k]);
}

// segmented graph-sum: wave handles 64 consecutive (gid-sorted) nodes, ~2 atomics/run
__global__ __launch_bounds__(256) void gsum_seg(const float* __restrict__ h,
                                                const int* __restrict__ gid,
                                                float* __restrict__ gf) {
    int wv = (blockIdx.x * 256 + threadIdx.x) >> 6;
    int lane = threadIdx.x & 63;
    int base = wv * 64;
    if (base >= N_NODES) return;
    int endn = min(base + 64, N_NODES);
    int cur = gid[base];
    float acc = 0.f;
    for (int n = base; n < endn; ++n) {
        int gg = gid[n];  // wave-uniform
        float v = h[(size_t)n * HID + lane] * 0.1f;
        if (gg != cur) {
            atomicAdd(&gf[(size_t)cur * HID + lane], acc);
            acc = v; cur = gg;
        } else acc += v;
    }
    atomicAdd(&gf[(size_t)cur * HID + lane], acc);
}

// ---------- fallback path (atomic aggregation) ----------

__global__ __launch_bounds__(256) void edge_kernel(
    const float* __restrict__ h, const float* __restrict__ pos,
    const float* __restrict__ edge_attr, const int* __restrict__ src,
    const int* __restrict__ dst, const float* __restrict__ Wm,
    const float* __restrict__ bm, float* __restrict__ agg)
{
    int e = blockIdx.x * 256 + threadIdx.x;
    if (e >= N_EDGES) return;
    float acc[HID]; int d;
    edge_msg_body(e, h, pos, edge_attr, src, dst, Wm, bm, acc, &d);
    float* a = agg + (size_t)d * HID;
    #pragma unroll
    for (int k = 0; k < HID; ++k) atomicAdd(a + k, silu_f(acc[k]));
}

__global__ __launch_bounds__(256) void gsum_kernel(
    const float* __restrict__ h, const int* __restrict__ gid, float* __restrict__ gf)
{
    int t = blockIdx.x * 256 + threadIdx.x;
    int n = t >> 6, k = t & 63;
    if (n >= N_NODES) return;
    atomicAdd(gf + gid[n] * HID + k, h[(size_t)n * HID + k] * 0.1f);
}

// one thread per graph: out = silu(gf @ Wh1 + bh1) @ Wh2 + bh2
__global__ __launch_bounds__(256) void head_kernel(
    const float* __restrict__ gf, const float* __restrict__ Wh1,
    const float* __restrict__ bh1, const float* __restrict__ Wh2,
    const float* __restrict__ bh2, float* __restrict__ out)
{
    int gi = blockIdx.x * 256 + threadIdx.x;
    if (gi >= N_GRAPHS) return;
    float x[HID];
    const float4* xr = (const float4*)(gf + (size_t)gi * HID);
    #pragma unroll
    for (int j4 = 0; j4 < 16; ++j4) {
        float4 v = xr[j4];
        x[4*j4] = v.x; x[4*j4+1] = v.y; x[4*j4+2] = v.z; x[4*j4+3] = v.w;
    }
    float o = bh2[0];
    #pragma unroll 4
    for (int j = 0; j < 32; ++j) {
        float hs_ = bh1[j];
        #pragma unroll
        for (int k = 0; k < HID; ++k) hs_ = fmaf(x[k], Wh1[k*32 + j], hs_);
        o = fmaf(silu_f(hs_), Wh2[j], o);
    }
    out[gi] = o;
}

extern "C" void kernel_launch(void* const* d_in, const int* in_sizes, int n_in,
                              void* d_out, int out_size, void* d_ws, size_t ws_size,
                              hipStream_t stream)
{
    const float* node_attr = (const float*)d_in[0];
    const float* pos       = (const float*)d_in[1];
    const float* edge_attr = (const float*)d_in[2];
    const int*   src       = (const int*)d_in[3];
    const int*   dst       = (const int*)d_in[4];
    const int*   gid       = (const int*)d_in[5];
    const float* Wm        = (const float*)d_in[6];
    const float* bm        = (const float*)d_in[7];
    const float* Wu        = (const float*)d_in[8];
    const float* bu        = (const float*)d_in[9];
    const float* ln_g      = (const float*)d_in[10];
    const float* ln_b      = (const float*)d_in[11];
    const float* Wh1       = (const float*)d_in[12];
    const float* bh1       = (const float*)d_in[13];
    const float* Wh2       = (const float*)d_in[14];
    const float* bh2       = (const float*)d_in[15];
    float* out = (float*)d_out;

    const int EB  = N_EDGES / 256;               // 6250
    const int NB  = (N_NODES + 255) / 256;       // 196
    const int SB  = (N_NODES + 1 + 255) / 256;   // 196 (covers row_ptr[N])
    const int ANB = ((N_NODES * 64) + 255) / 256;  // 12500 (wave per node)
    const int GSB = ((((N_NODES + 63) / 64) * 64) + 255) / 256;

    // ---- workspace layout (fixed part ~33 MB, then msg chunk buffer) ----
    float* B1  = (float*)d_ws;                               // N*64
    float* B2  = B1 + (size_t)N_NODES * HID;                 // N*64
    float* gf  = B2 + (size_t)N_NODES * HID;                 // G*64
    int* deg   = (int*)(gf + (size_t)N_GRAPHS * HID);        // N
    int* fill  = deg + N_NODES;                              // N
    int* rp    = fill + N_NODES;                             // N+1
    int* part  = rp + N_NODES + 1;                           // 256
    int* pscan = part + 256;                                 // 256
    int* eids  = pscan + 256;                                // E
    // align msg to 16B
    uintptr_t msg_addr = ((uintptr_t)(eids + N_EDGES) + 15u) & ~(uintptr_t)15u;
    float* msg = (float*)msg_addr;
    size_t fixed_bytes = msg_addr - (uintptr_t)d_ws;

    long long chunk_cap = 0;
    if (ws_size > fixed_bytes)
        chunk_cap = (long long)((ws_size - fixed_bytes) / (HID * sizeof(float)));
    if (chunk_cap > N_EDGES) chunk_cap = N_EDGES;

    if (chunk_cap >= 65536) {
        // ---- fast path: CSR + chunked dense messages, no f32 atomics ----
        hipMemsetAsync(deg, 0, (size_t)N_NODES * 2 * sizeof(int), stream);  // deg + fill
        csr_count<<<EB, 256, 0, stream>>>(dst, deg);
        scan_blocks<<<SB, 256, 0, stream>>>(deg, rp, part);
        scan_partials<<<1, 256, 0, stream>>>(part, pscan, SB);
        add_offsets<<<SB, 256, 0, stream>>>(rp, pscan);
        csr_fill<<<EB, 256, 0, stream>>>(dst, rp, fill, eids);

        const int C = (int)chunk_cap;
        const int nchunks = (N_EDGES + C - 1) / C;

        const float* hin = node_attr;
        float* bufs[3] = { B1, B2, B1 };
        for (int i = 0; i < 3; ++i) {
            float* aggb = bufs[i];
            hipMemsetAsync(aggb, 0, (size_t)N_NODES * HID * sizeof(float), stream);
            for (int c = 0; c < nchunks; ++c) {
                int t0 = c * C;
                int t1 = min(t0 + C, N_EDGES);
                int cb = (t1 - t0 + 255) / 256;
                edge_msg_sorted<<<cb, 256, 0, stream>>>(hin, pos, edge_attr, src, dst, eids,
                                                        Wm + (size_t)i * 145 * HID, bm + i * HID,
                                                        msg, t0, t1);
                agg_chunk<<<ANB, 256, 0, stream>>>(msg, rp, aggb, t0, t1);
            }
            node_kernel<<<NB, 256, 0, stream>>>(aggb, Wu + (size_t)i * HID * HID, bu + i * HID,
                                                ln_g + i * HID, ln_b + i * HID);
            hin = aggb;
        }
        hipMemsetAsync(gf, 0, (size_t)N_GRAPHS * HID * sizeof(float), stream);
        gsum_seg<<<GSB, 256, 0, stream>>>(hin, gid, gf);
        head_kernel<<<(N_GRAPHS + 255) / 256, 256, 0, stream>>>(gf, Wh1, bh1, Wh2, bh2, out);
    } else {
        // ---- fallback: atomic aggregation (verified correct, 16.4 ms) ----
        float* fB1 = (float*)d_ws;
        float* fB2 = fB1 + (size_t)N_NODES * HID;
        float* fgf = fB2 + (size_t)N_NODES * HID;
        const float* hin = node_attr;
        float* bufs[3] = { fB1, fB2, fB1 };
        for (int i = 0; i < 3; ++i) {
            float* agg = bufs[i];
            hipMemsetAsync(agg, 0, (size_t)N_NODES * HID * sizeof(float), stream);
            edge_kernel<<<EB, 256, 0, stream>>>(hin, pos, edge_attr, src, dst,
                                                Wm + (size_t)i * 145 * HID, bm + i * HID, agg);
            node_kernel<<<NB, 256, 0, stream>>>(agg, Wu + (size_t)i * HID * HID, bu + i * HID,
                                                ln_g + i * HID, ln_b + i * HID);
            hin = agg;
        }
        hipMemsetAsync(fgf, 0, (size_t)N_GRAPHS * HID * sizeof(float), stream);
        gsum_kernel<<<(N_NODES * 64) / 256, 256, 0, stream>>>(hin, gid, fgf);
        head_kernel<<<(N_GRAPHS + 255) / 256, 256, 0, stream>>>(fgf, Wh1, bh1, Wh2, bh2, out);
    }
}

// Round 15
// 1471.042 us; speedup vs baseline: 11.1818x; 1.7896x over previous
//
#include <hip/hip_runtime.h>

#define N_NODES 50000
#define N_EDGES 1600000
#define N_GRAPHS 1024
#define HID 64
#define EDGE_F 16
#define LN_EPS 1e-5f

__device__ __forceinline__ float silu_f(float x) {
    return x / (1.0f + __expf(-x));
}

// acc[k] += scale * x[j] * w[j*HID + k]; w accesses wave-uniform -> s_load + SGPR-operand v_fma.
template<int NJ4>
__device__ __forceinline__ void gemv_acc(const float4* __restrict__ x,
                                         const float* __restrict__ w,
                                         float scale, float* __restrict__ acc) {
    for (int j4 = 0; j4 < NJ4; ++j4) {
        float4 v = x[j4];
        v.x *= scale; v.y *= scale; v.z *= scale; v.w *= scale;
        const float* wr = w + j4 * 4 * HID;
        #pragma unroll
        for (int k = 0; k < HID; ++k) acc[k] = fmaf(v.x, wr[k],         acc[k]);
        #pragma unroll
        for (int k = 0; k < HID; ++k) acc[k] = fmaf(v.y, wr[HID + k],   acc[k]);
        #pragma unroll
        for (int k = 0; k < HID; ++k) acc[k] = fmaf(v.z, wr[2*HID + k], acc[k]);
        #pragma unroll
        for (int k = 0; k < HID; ++k) acc[k] = fmaf(v.w, wr[3*HID + k], acc[k]);
    }
}

// ---------- CSR build (verified R12) ----------

__global__ __launch_bounds__(256) void csr_count(const int* __restrict__ dst, int* __restrict__ deg) {
    int e = blockIdx.x * 256 + threadIdx.x;
    if (e < N_EDGES) atomicAdd(&deg[dst[e]], 1);
}

__global__ __launch_bounds__(256) void scan_blocks(const int* __restrict__ deg,
                                                   int* __restrict__ row_ptr,
                                                   int* __restrict__ partial) {
    __shared__ int sm[256];
    int i = blockIdx.x * 256 + threadIdx.x;
    int v = (i < N_NODES) ? deg[i] : 0;
    sm[threadIdx.x] = v;
    __syncthreads();
    for (int off = 1; off < 256; off <<= 1) {
        int t = (threadIdx.x >= off) ? sm[threadIdx.x - off] : 0;
        __syncthreads();
        sm[threadIdx.x] += t;
        __syncthreads();
    }
    if (i <= N_NODES) row_ptr[i] = sm[threadIdx.x] - v;  // exclusive
    if (threadIdx.x == 255) partial[blockIdx.x] = sm[255];
}

__global__ __launch_bounds__(256) void scan_partials(const int* __restrict__ partial,
                                                     int* __restrict__ pscan, int nb) {
    __shared__ int sm[256];
    int v = (threadIdx.x < nb) ? partial[threadIdx.x] : 0;
    sm[threadIdx.x] = v;
    __syncthreads();
    for (int off = 1; off < 256; off <<= 1) {
        int t = (threadIdx.x >= off) ? sm[threadIdx.x - off] : 0;
        __syncthreads();
        sm[threadIdx.x] += t;
        __syncthreads();
    }
    pscan[threadIdx.x] = sm[threadIdx.x] - v;  // exclusive
}

__global__ __launch_bounds__(256) void add_offsets(int* __restrict__ row_ptr,
                                                   const int* __restrict__ pscan) {
    int i = blockIdx.x * 256 + threadIdx.x;
    if (i <= N_NODES) row_ptr[i] += pscan[blockIdx.x];
}

__global__ __launch_bounds__(256) void csr_fill(const int* __restrict__ dst,
                                                const int* __restrict__ row_ptr,
                                                int* __restrict__ fill, int* __restrict__ eids) {
    int e = blockIdx.x * 256 + threadIdx.x;
    if (e >= N_EDGES) return;
    int d = dst[e];
    int slot = atomicAdd(&fill[d], 1);
    eids[row_ptr[d] + slot] = e;
}

// once per launch: CSR-ordered src, dij, and (optionally) permuted edge_attr
__global__ __launch_bounds__(256) void permute_edges(
    const int* __restrict__ src, const int* __restrict__ dst,
    const float* __restrict__ pos, const float* __restrict__ edge_attr,
    const int* __restrict__ eids, int* __restrict__ ssorted,
    float* __restrict__ dijs, float* __restrict__ ea_s, int use_perm)
{
    int t = blockIdx.x * 256 + threadIdx.x;
    if (t >= N_EDGES) return;
    int e = eids[t];
    int s = src[e], d = dst[e];
    ssorted[t] = s;
    float px = pos[3*s+0] - pos[3*d+0];
    float py = pos[3*s+1] - pos[3*d+1];
    float pz = pos[3*s+2] - pos[3*d+2];
    dijs[t] = sqrtf(fmaxf(px*px + py*py + pz*pz, 1e-8f));
    if (use_perm) {
        const float4* ei = (const float4*)(edge_attr + (size_t)e * EDGE_F);
        float4* eo = (float4*)(ea_s + (size_t)t * EDGE_F);
        eo[0] = ei[0]; eo[1] = ei[1]; eo[2] = ei[2]; eo[3] = ei[3];
    }
}

// per conv: hs_part = h@Wm1, hd_part = h@Wm2 + bm (thread per node)
__global__ __launch_bounds__(256) void part_kernel(
    const float* __restrict__ h, const float* __restrict__ Wm,
    const float* __restrict__ bm, float* __restrict__ hs_part,
    float* __restrict__ hd_part)
{
    int n = blockIdx.x * 256 + threadIdx.x;
    if (n >= N_NODES) return;
    float a1[HID], a2[HID];
    #pragma unroll
    for (int k = 0; k < HID; ++k) { a1[k] = 0.f; a2[k] = bm[k]; }
    const float4* xr = (const float4*)(h + (size_t)n * HID);
    gemv_acc<16>(xr, Wm,            1.0f, a1);
    gemv_acc<16>(xr, Wm + 64*HID,   1.0f, a2);
    float4* o1 = (float4*)(hs_part + (size_t)n * HID);
    float4* o2 = (float4*)(hd_part + (size_t)n * HID);
    #pragma unroll
    for (int k4 = 0; k4 < 16; ++k4) {
        o1[k4] = make_float4(a1[4*k4], a1[4*k4+1], a1[4*k4+2], a1[4*k4+3]);
        o2[k4] = make_float4(a2[4*k4], a2[4*k4+1], a2[4*k4+2], a2[4*k4+3]);
    }
}

// fused message+aggregate: one 64-lane wave per node, lane = feature.
// per edge: pre = hd_part[n] + hs_part[s] + dij*wd + ea@Wea; acc += silu(pre)
__global__ __launch_bounds__(256) void fused_agg(
    const float* __restrict__ hs_part, const float* __restrict__ hd_part,
    const int* __restrict__ ssorted, const float* __restrict__ dijs,
    const float* __restrict__ ea, const int* __restrict__ eids, int use_perm,
    const float* __restrict__ Wm, const int* __restrict__ rp,
    float* __restrict__ aggbuf)
{
    int wid = (blockIdx.x * 256 + threadIdx.x) >> 6;
    int lane = threadIdx.x & 63;
    if (wid >= N_NODES) return;
    int beg = rp[wid], end = rp[wid + 1];

    float base = hd_part[(size_t)wid * HID + lane];   // includes bm
    float wdk  = Wm[128 * HID + lane];
    float wea[EDGE_F];
    #pragma unroll
    for (int j = 0; j < EDGE_F; ++j) wea[j] = Wm[(129 + j) * HID + lane];

    float acc = 0.f;
    for (int t = beg; t < end; ++t) {
        int s = ssorted[t];           // wave-uniform
        float dij = dijs[t];          // wave-uniform
        float pre = fmaf(dij, wdk, base) + hs_part[(size_t)s * HID + lane];
        const float4* er = (const float4*)(use_perm ? (ea + (size_t)t * EDGE_F)
                                                    : (ea + (size_t)eids[t] * EDGE_F));
        float4 e0 = er[0], e1 = er[1], e2 = er[2], e3 = er[3];
        pre = fmaf(e0.x, wea[0],  pre); pre = fmaf(e0.y, wea[1],  pre);
        pre = fmaf(e0.z, wea[2],  pre); pre = fmaf(e0.w, wea[3],  pre);
        pre = fmaf(e1.x, wea[4],  pre); pre = fmaf(e1.y, wea[5],  pre);
        pre = fmaf(e1.z, wea[6],  pre); pre = fmaf(e1.w, wea[7],  pre);
        pre = fmaf(e2.x, wea[8],  pre); pre = fmaf(e2.y, wea[9],  pre);
        pre = fmaf(e2.z, wea[10], pre); pre = fmaf(e2.w, wea[11], pre);
        pre = fmaf(e3.x, wea[12], pre); pre = fmaf(e3.y, wea[13], pre);
        pre = fmaf(e3.z, wea[14], pre); pre = fmaf(e3.w, wea[15], pre);
        acc += silu_f(pre);
    }
    aggbuf[(size_t)wid * HID + lane] = acc;   // plain store, no memset needed
}

// one thread per node: u = silu((agg/10) @ Wu + bu); h_out = LN(u)*g + b. In-place on agg. (verified)
__global__ __launch_bounds__(256) void node_kernel(
    float* __restrict__ agg, const float* __restrict__ Wu,
    const float* __restrict__ bu, const float* __restrict__ g,
    const float* __restrict__ b)
{
    int n = blockIdx.x * 256 + threadIdx.x;
    if (n >= N_NODES) return;
    float acc[HID];
    #pragma unroll
    for (int k = 0; k < HID; ++k) acc[k] = bu[k];
    gemv_acc<16>((const float4*)(agg + (size_t)n * HID), Wu, 0.1f, acc);
    float mu = 0.f;
    #pragma unroll
    for (int k = 0; k < HID; ++k) { acc[k] = silu_f(acc[k]); mu += acc[k]; }
    mu *= (1.0f / HID);
    float var = 0.f;
    #pragma unroll
    for (int k = 0; k < HID; ++k) { float t = acc[k] - mu; var += t * t; }
    var *= (1.0f / HID);
    float rs = rsqrtf(var + LN_EPS);
    float* o = agg + (size_t)n * HID;
    #pragma unroll
    for (int k = 0; k < HID; ++k) o[k] = fmaf(g[k], (acc[k] - mu) * rs, b[k]);
}

// segmented graph-sum (verified R12)
__global__ __launch_bounds__(256) void gsum_seg(const float* __restrict__ h,
                                                const int* __restrict__ gid,
                                                float* __restrict__ gf) {
    int wv = (blockIdx.x * 256 + threadIdx.x) >> 6;
    int lane = threadIdx.x & 63;
    int base = wv * 64;
    if (base >= N_NODES) return;
    int endn = min(base + 64, N_NODES);
    int cur = gid[base];
    float acc = 0.f;
    for (int n = base; n < endn; ++n) {
        int gg = gid[n];  // wave-uniform
        float v = h[(size_t)n * HID + lane] * 0.1f;
        if (gg != cur) {
            atomicAdd(&gf[(size_t)cur * HID + lane], acc);
            acc = v; cur = gg;
        } else acc += v;
    }
    atomicAdd(&gf[(size_t)cur * HID + lane], acc);
}

// ---------- fallback path (atomic aggregation, verified R3/R10) ----------

__device__ __forceinline__ void edge_msg_body(int e,
    const float* __restrict__ h, const float* __restrict__ pos,
    const float* __restrict__ edge_attr, const int* __restrict__ src,
    const int* __restrict__ dst, const float* __restrict__ Wm,
    const float* __restrict__ bm, float* __restrict__ acc, int* d_out)
{
    int s = src[e], d = dst[e];
    *d_out = d;
    float px = pos[3*s+0] - pos[3*d+0];
    float py = pos[3*s+1] - pos[3*d+1];
    float pz = pos[3*s+2] - pos[3*d+2];
    float dij = sqrtf(fmaxf(px*px + py*py + pz*pz, 1e-8f));
    #pragma unroll
    for (int k = 0; k < HID; ++k) acc[k] = bm[k];
    gemv_acc<16>((const float4*)(h + (size_t)s * HID), Wm,          1.0f, acc);
    gemv_acc<16>((const float4*)(h + (size_t)d * HID), Wm + 64*HID, 1.0f, acc);
    {
        const float* wr = Wm + 128*HID;
        #pragma unroll
        for (int k = 0; k < HID; ++k) acc[k] = fmaf(dij, wr[k], acc[k]);
    }
    gemv_acc<4>((const float4*)(edge_attr + (size_t)e * EDGE_F), Wm + 129*HID, 1.0f, acc);
}

__global__ __launch_bounds__(256) void edge_kernel(
    const float* __restrict__ h, const float* __restrict__ pos,
    const float* __restrict__ edge_attr, const int* __restrict__ src,
    const int* __restrict__ dst, const float* __restrict__ Wm,
    const float* __restrict__ bm, float* __restrict__ agg)
{
    int e = blockIdx.x * 256 + threadIdx.x;
    if (e >= N_EDGES) return;
    float acc[HID]; int d;
    edge_msg_body(e, h, pos, edge_attr, src, dst, Wm, bm, acc, &d);
    float* a = agg + (size_t)d * HID;
    #pragma unroll
    for (int k = 0; k < HID; ++k) atomicAdd(a + k, silu_f(acc[k]));
}

__global__ __launch_bounds__(256) void gsum_kernel(
    const float* __restrict__ h, const int* __restrict__ gid, float* __restrict__ gf)
{
    int t = blockIdx.x * 256 + threadIdx.x;
    int n = t >> 6, k = t & 63;
    if (n >= N_NODES) return;
    atomicAdd(gf + gid[n] * HID + k, h[(size_t)n * HID + k] * 0.1f);
}

// one thread per graph: out = silu(gf @ Wh1 + bh1) @ Wh2 + bh2 (verified)
__global__ __launch_bounds__(256) void head_kernel(
    const float* __restrict__ gf, const float* __restrict__ Wh1,
    const float* __restrict__ bh1, const float* __restrict__ Wh2,
    const float* __restrict__ bh2, float* __restrict__ out)
{
    int gi = blockIdx.x * 256 + threadIdx.x;
    if (gi >= N_GRAPHS) return;
    float x[HID];
    const float4* xr = (const float4*)(gf + (size_t)gi * HID);
    #pragma unroll
    for (int j4 = 0; j4 < 16; ++j4) {
        float4 v = xr[j4];
        x[4*j4] = v.x; x[4*j4+1] = v.y; x[4*j4+2] = v.z; x[4*j4+3] = v.w;
    }
    float o = bh2[0];
    #pragma unroll 4
    for (int j = 0; j < 32; ++j) {
        float hs_ = bh1[j];
        #pragma unroll
        for (int k = 0; k < HID; ++k) hs_ = fmaf(x[k], Wh1[k*32 + j], hs_);
        o = fmaf(silu_f(hs_), Wh2[j], o);
    }
    out[gi] = o;
}

extern "C" void kernel_launch(void* const* d_in, const int* in_sizes, int n_in,
                              void* d_out, int out_size, void* d_ws, size_t ws_size,
                              hipStream_t stream)
{
    const float* node_attr = (const float*)d_in[0];
    const float* pos       = (const float*)d_in[1];
    const float* edge_attr = (const float*)d_in[2];
    const int*   src       = (const int*)d_in[3];
    const int*   dst       = (const int*)d_in[4];
    const int*   gid       = (const int*)d_in[5];
    const float* Wm        = (const float*)d_in[6];
    const float* bm        = (const float*)d_in[7];
    const float* Wu        = (const float*)d_in[8];
    const float* bu        = (const float*)d_in[9];
    const float* ln_g      = (const float*)d_in[10];
    const float* ln_b      = (const float*)d_in[11];
    const float* Wh1       = (const float*)d_in[12];
    const float* bh1       = (const float*)d_in[13];
    const float* Wh2       = (const float*)d_in[14];
    const float* bh2       = (const float*)d_in[15];
    float* out = (float*)d_out;

    const int EB  = N_EDGES / 256;                 // 6250
    const int NB  = (N_NODES + 255) / 256;         // 196
    const int SB  = (N_NODES + 1 + 255) / 256;     // 196
    const int ANB = ((N_NODES * 64) + 255) / 256;  // 12500 (wave per node)
    const int GSB = ((((N_NODES + 63) / 64) * 64) + 255) / 256;

    // ---- workspace layout ----
    float* B1   = (float*)d_ws;                              // N*64
    float* B2   = B1 + (size_t)N_NODES * HID;                // N*64
    float* gf   = B2 + (size_t)N_NODES * HID;                // G*64
    float* hsP  = gf + (size_t)N_GRAPHS * HID;               // N*64
    float* hdP  = hsP + (size_t)N_NODES * HID;               // N*64
    int* deg    = (int*)(hdP + (size_t)N_NODES * HID);       // N
    int* fill   = deg + N_NODES;                             // N
    int* rp     = fill + N_NODES;                            // N+1
    int* part   = rp + N_NODES + 1;                          // 256
    int* pscan  = part + 256;                                // 256
    int* eids   = pscan + 256;                               // E
    int* ssort  = eids + N_EDGES;                            // E
    float* dijs = (float*)(ssort + N_EDGES);                 // E
    uintptr_t ea_addr = ((uintptr_t)(dijs + N_EDGES) + 15u) & ~(uintptr_t)15u;
    float* ea_s = (float*)ea_addr;                           // E*16 (optional)
    size_t need_noea = ea_addr - (uintptr_t)d_ws;
    size_t need_ea   = need_noea + (size_t)N_EDGES * EDGE_F * sizeof(float);

    if (ws_size >= need_noea) {
        int use_perm = (ws_size >= need_ea) ? 1 : 0;
        const float* ea_ptr = use_perm ? ea_s : edge_attr;

        // CSR build (once per launch)
        hipMemsetAsync(deg, 0, (size_t)N_NODES * 2 * sizeof(int), stream);  // deg + fill
        csr_count<<<EB, 256, 0, stream>>>(dst, deg);
        scan_blocks<<<SB, 256, 0, stream>>>(deg, rp, part);
        scan_partials<<<1, 256, 0, stream>>>(part, pscan, SB);
        add_offsets<<<SB, 256, 0, stream>>>(rp, pscan);
        csr_fill<<<EB, 256, 0, stream>>>(dst, rp, fill, eids);
        permute_edges<<<EB, 256, 0, stream>>>(src, dst, pos, edge_attr, eids,
                                              ssort, dijs, ea_s, use_perm);

        const float* hin = node_attr;
        float* bufs[3] = { B1, B2, B1 };
        for (int i = 0; i < 3; ++i) {
            const float* Wmi = Wm + (size_t)i * 145 * HID;
            part_kernel<<<NB, 256, 0, stream>>>(hin, Wmi, bm + i * HID, hsP, hdP);
            fused_agg<<<ANB, 256, 0, stream>>>(hsP, hdP, ssort, dijs, ea_ptr, eids,
                                               use_perm, Wmi, rp, bufs[i]);
            node_kernel<<<NB, 256, 0, stream>>>(bufs[i], Wu + (size_t)i * HID * HID,
                                                bu + i * HID, ln_g + i * HID, ln_b + i * HID);
            hin = bufs[i];
        }
        hipMemsetAsync(gf, 0, (size_t)N_GRAPHS * HID * sizeof(float), stream);
        gsum_seg<<<GSB, 256, 0, stream>>>(hin, gid, gf);
        head_kernel<<<(N_GRAPHS + 255) / 256, 256, 0, stream>>>(gf, Wh1, bh1, Wh2, bh2, out);
    } else {
        // fallback: atomic aggregation (verified, 16.4 ms)
        float* fB1 = (float*)d_ws;
        float* fB2 = fB1 + (size_t)N_NODES * HID;
        float* fgf = fB2 + (size_t)N_NODES * HID;
        const float* hin = node_attr;
        float* bufs[3] = { fB1, fB2, fB1 };
        for (int i = 0; i < 3; ++i) {
            float* agg = bufs[i];
            hipMemsetAsync(agg, 0, (size_t)N_NODES * HID * sizeof(float), stream);
            edge_kernel<<<EB, 256, 0, stream>>>(hin, pos, edge_attr, src, dst,
                                                Wm + (size_t)i * 145 * HID, bm + i * HID, agg);
            node_kernel<<<NB, 256, 0, stream>>>(agg, Wu + (size_t)i * HID * HID, bu + i * HID,
                                                ln_g + i * HID, ln_b + i * HID);
            hin = agg;
        }
        hipMemsetAsync(fgf, 0, (size_t)N_GRAPHS * HID * sizeof(float), stream);
        gsum_kernel<<<(N_NODES * 64) / 256, 256, 0, stream>>>(hin, gid, fgf);
        head_kernel<<<(N_GRAPHS + 255) / 256, 256, 0, stream>>>(fgf, Wh1, bh1, Wh2, bh2, out);
    }
}